// Round 5
// baseline (511.315 us; speedup 1.0000x reference)
//
#include <hip/hip_runtime.h>
#include <hip/hip_bf16.h>
#include <stdint.h>

typedef __bf16 bf16;
typedef short short8 __attribute__((ext_vector_type(8)));   // bf16 A/B frag (bit pattern)
typedef float f32x4 __attribute__((ext_vector_type(4)));

#define LOG2E 1.4426950408889634f

union V16 { uint4 u; short8 s; bf16 h[8]; };
union U8  { ushort4 s; bf16 h[4]; };

typedef const __attribute__((address_space(1))) void* gp_t;
typedef __attribute__((address_space(3))) void* lp_t;
__device__ __forceinline__ void gld16(const bf16* g, bf16* l) {
  __builtin_amdgcn_global_load_lds((gp_t)g, (lp_t)l, 16, 0, 0);
}

// LDS-only barrier: drains lgkmcnt (LDS ops) but NOT vmcnt, so global loads
// issued before it stay in flight across the barrier (rule #18: sched_barrier
// fences prevent hipcc hoisting LDS ops across the asm waitcnt).
__device__ __forceinline__ void barrier_lds() {
  __builtin_amdgcn_sched_barrier(0);
  asm volatile("s_waitcnt lgkmcnt(0)" ::: "memory");
  __builtin_amdgcn_s_barrier();
  __builtin_amdgcn_sched_barrier(0);
}

// ---- kernel Z: zero a float4 range ---------------------------------------
__global__ __launch_bounds__(256) void k_zero(float4* __restrict__ p, int n4) {
  int i = blockIdx.x * 256 + threadIdx.x;
  if (i < n4) p[i] = {0.f, 0.f, 0.f, 0.f};
}

// ---- kernel 0: f32 -> bf16 bulk convert (n multiple of 8) ---------------
__global__ __launch_bounds__(256) void k_cvt(const float* __restrict__ src,
                                             bf16* __restrict__ dst, long long n) {
  long long i = ((long long)blockIdx.x * 256 + threadIdx.x) * 8;
  if (i >= n) return;
  float4 a = *(const float4*)(src + i);
  float4 b = *(const float4*)(src + i + 4);
  U8 w0, w1;
  w0.h[0] = (bf16)a.x; w0.h[1] = (bf16)a.y; w0.h[2] = (bf16)a.z; w0.h[3] = (bf16)a.w;
  w1.h[0] = (bf16)b.x; w1.h[1] = (bf16)b.y; w1.h[2] = (bf16)b.z; w1.h[3] = (bf16)b.w;
  *(ushort4*)(dst + i)     = w0.s;
  *(ushort4*)(dst + i + 4) = w1.s;
}

// ---- kernel 1: pack adjacency rows into 512-bit masks -------------------
__global__ __launch_bounds__(256) void k_maskpack(const int* __restrict__ adj,
                                                  unsigned long long* __restrict__ mask) {
  int wid = blockIdx.x * 4 + (threadIdx.x >> 6);
  int lane = threadIdx.x & 63;
  int a = adj[(long long)wid * 64 + lane];
  unsigned long long m = __ballot(a > 0);
  if (lane == 0) mask[wid] = m;
}

// ---- kernel 2: f32 [R,C] -> bf16 [C,R] transpose+convert per z-slice ----
__global__ __launch_bounds__(256) void k_transpose(const float* __restrict__ src,
                                                   bf16* __restrict__ dst, int R, int C) {
  __shared__ float t[32][33];
  int c0 = blockIdx.x * 32, r0 = blockIdx.y * 32;
  src += (long long)blockIdx.z * R * C;
  dst += (long long)blockIdx.z * R * C;
  int tx = threadIdx.x & 31, ty = threadIdx.x >> 5;
  for (int rr = ty; rr < 32; rr += 8)
    t[rr][tx] = src[(long long)(r0 + rr) * C + (c0 + tx)];
  __syncthreads();
  for (int cc = ty; cc < 32; cc += 8)
    dst[(long long)(c0 + cc) * R + (r0 + tx)] = (bf16)t[tx][cc];
}

// ---- kernel 3: bf16 MFMA GEMM + fused f1/f2 dot epilogue ----------------
// Output layout: MFMA-fragment-swizzled Wf. 8-bf16 chunk index:
//   C = ((hb*16 + ft)*16 + js)*64 + quad*16 + lrow
// A k_pv wave then reads frag (ni,js) as base + lane*8 elems: coalesced 1KB.
__global__ __launch_bounds__(256) void k_gemm(const bf16* __restrict__ A,
                                              const bf16* __restrict__ WT,
                                              bf16* __restrict__ outT, int K,
                                              const float* __restrict__ a1,
                                              const float* __restrict__ a2,
                                              int aStride,
                                              float* __restrict__ f1out,
                                              float* __restrict__ f2out) {
  __shared__ bf16 As[128 * 32];      // unpadded: global_load_lds lane order
  __shared__ bf16 Bs[128 * 32];
  const int nb = blockIdx.x, mb = blockIdx.y, h = blockIdx.z;
  const int tid = threadIdx.x, wave = tid >> 6, lane = tid & 63;
  const int lrow = lane & 15, quad = lane >> 4;
  const long long mbase = (long long)mb * 128;
  const int nbase = nb * 128;
  const bf16* W = WT + (long long)h * 256 * K;
  const int wm = (wave >> 1) * 64, wn = (wave & 1) * 64;
  const int srow = wave * 16 + (lane >> 2);
  const int skoff = (lane & 3) * 8;
  const bf16* ag0 = A + (mbase + srow) * K + skoff;
  const bf16* ag1 = ag0 + 64 * K;
  const bf16* bg0 = W + (long long)(nbase + srow) * K + skoff;
  const bf16* bg1 = bg0 + 64 * K;
  bf16* lA0 = As + wave * 16 * 32;
  bf16* lA1 = As + (64 + wave * 16) * 32;
  bf16* lB0 = Bs + wave * 16 * 32;
  bf16* lB1 = Bs + (64 + wave * 16) * 32;
  f32x4 acc[4][4];
#pragma unroll
  for (int i = 0; i < 4; i++)
#pragma unroll
    for (int j = 0; j < 4; j++) acc[i][j] = {0.f, 0.f, 0.f, 0.f};
  for (int k0 = 0; k0 < K; k0 += 32) {
    __syncthreads();                 // prior frag reads complete before overwrite
    gld16(ag0 + k0, lA0);
    gld16(ag1 + k0, lA1);
    gld16(bg0 + k0, lB0);
    gld16(bg1 + k0, lB1);
    __syncthreads();                 // vmcnt(0) drain: tile landed
    V16 af[4], bfx[4];
#pragma unroll
    for (int mi = 0; mi < 4; mi++)
      af[mi].u = *(const uint4*)(As + (wm + mi * 16 + lrow) * 32 + quad * 8);
#pragma unroll
    for (int ni = 0; ni < 4; ni++)
      bfx[ni].u = *(const uint4*)(Bs + (wn + ni * 16 + lrow) * 32 + quad * 8);
#pragma unroll
    for (int mi = 0; mi < 4; mi++)
#pragma unroll
      for (int ni = 0; ni < 4; ni++)
        acc[mi][ni] = __builtin_amdgcn_mfma_f32_16x16x32_bf16(af[mi].s, bfx[ni].s, acc[mi][ni], 0, 0, 0);
  }
  // D frag: col(lane&15) -> f, row(quad*4+r) -> node; write frag-swizzled
#pragma unroll
  for (int mi = 0; mi < 4; mi++) {
    long long m0 = mbase + wm + mi * 16 + quad * 4;
    int bbi = (int)(m0 >> 9);
    int jj = (int)(m0 & 511);
    int js = jj >> 5, qp = (jj >> 3) & 3, eo = jj & 7;
    long long rowbase = (long long)(h * 32 + bbi) * 131072 +
                        (long long)js * 512 + (qp * 16 + lrow) * 8 + eo;
#pragma unroll
    for (int ni = 0; ni < 4; ni++) {
      int ft = ((nbase + wn) >> 4) + ni;
      U8 w;
#pragma unroll
      for (int r = 0; r < 4; r++) w.h[r] = (bf16)acc[mi][ni][r];
      *(ushort4*)(outT + rowbase + (long long)ft * 8192) = w.s;
    }
  }
  // ---- fused f1/f2 partial dots (raw units; LOG2E applied downstream) ----
  float av1[4], av2[4];
#pragma unroll
  for (int ni = 0; ni < 4; ni++) {
    int f = nbase + wn + ni * 16 + lrow;
    av1[ni] = a1[h * aStride + f];
    av2[ni] = a2[h * aStride + f];
  }
#pragma unroll
  for (int mi = 0; mi < 4; mi++) {
#pragma unroll
    for (int r = 0; r < 4; r++) {
      float s1 = 0.f, s2 = 0.f;
#pragma unroll
      for (int ni = 0; ni < 4; ni++) {
        s1 = __builtin_fmaf(acc[mi][ni][r], av1[ni], s1);
        s2 = __builtin_fmaf(acc[mi][ni][r], av2[ni], s2);
      }
#pragma unroll
      for (int off = 1; off < 16; off <<= 1) {
        s1 += __shfl_xor(s1, off);
        s2 += __shfl_xor(s2, off);
      }
      if (lrow == 0) {
        long long m0 = mbase + wm + mi * 16 + quad * 4 + r;
        atomicAdd(&f1out[(long long)h * 16384 + m0], s1);
        atomicAdd(&f2out[(long long)h * 16384 + m0], s2);
      }
    }
  }
}

// ---- kernel 6: fused masked-softmax PV (passA folded in) ----------------
// Grid = NSPLIT * 32 * (512/ROWS) blocks; id low bits = bb (XCD/L2 locality).
// Per head: two-pass in-register softmax builds UNNORMALIZED P in LDS
// (row-max + denom via TPR-lane shfl reduce; 1/d applied to the f32
// accumulator after the MFMA loop). B fragments read direct from L2 in the
// frag-swizzled layout, 1-deep register prefetch; barriers are LDS-only so
// B loads stay in flight across them.
// MODE0: elu + head-partial sum -> f32 partial buffer out0/out1 (by hp).
// MODE1: relu -> f32 final output.
__device__ __forceinline__ int pchunk(int row, int c) {   // bf16 index of 8-elem chunk
  return row * 512 + (((c + 3 * row) & 63) << 3);
}

template <int NSPLIT, int NHB, int ROWS, int MODE>
__global__ __launch_bounds__(256) void k_pv(const bf16* __restrict__ WhT,
                                            const float* __restrict__ f1p,
                                            const float* __restrict__ f2p,
                                            const unsigned long long* __restrict__ mask,
                                            void* __restrict__ out0,
                                            void* __restrict__ out1) {
  constexpr int TPR = 256 / ROWS;          // threads per P row (8 or 16)
  constexpr int NT  = 64 / TPR;            // mask bytes (col-chunks) per thread
  constexpr int MI  = ROWS / 16;           // 16-row MFMA sub-blocks
  constexpr int RB  = 32 * (512 / ROWS);   // blocks per head-group
  constexpr int CPT = 256 / TPR;           // output cols per thread
  __shared__ union { bf16 P[ROWS * 512]; float hs[ROWS * 264]; } sh;
  __shared__ float dinvs[ROWS];
  __shared__ unsigned char ms[ROWS * 64];
  const int id = blockIdx.x;
  const int hp = id / RB;                  // head-group index (0..NSPLIT-1)
  const int rid = id % RB;
  const int bb = rid & 31, it = rid >> 5;
  const int ibase = it * ROWS;
  const int tid = threadIdx.x, wave = tid >> 6, lane = tid & 63;
  const int lrow = lane & 15, quad = lane >> 4;
  const int pi = tid / TPR;                // P row
  const int pj = tid % TPR;                // column-chunk owner within the row
  {
    const uint4* msrc = (const uint4*)(mask + ((long long)bb * 512 + ibase) * 8);
    if (tid < ROWS * 4) ((uint4*)ms)[tid] = msrc[tid];
  }
  barrier_lds();
  unsigned long long mreg = 0;
#pragma unroll
  for (int t = 0; t < NT; t++)
    mreg |= (unsigned long long)ms[pi * 64 + pj + t * TPR] << (t * 8);
  f32x4 hacc[MI][4];
#pragma unroll
  for (int i = 0; i < MI; i++)
#pragma unroll
    for (int j = 0; j < 4; j++) hacc[i][j] = {0.f, 0.f, 0.f, 0.f};

  // fused softmax P-build: pass1 masked row-max, pass2 unnormalized exp2,
  // denominator reduced over the row's TPR lanes; dinv -> LDS.
  auto buildP = [&](int h) {
    const int hb = h * 32 + bb;
    const float F1L = LOG2E * f1p[hb * 512 + ibase + pi];
    const float* f2 = f2p + (long long)hb * 512;
    float mx = -INFINITY;
#pragma unroll
    for (int t = 0; t < NT; t++) {
      const int j0 = (pj + t * TPR) * 8;
      float4 u0 = *(const float4*)(f2 + j0);
      float4 u1 = *(const float4*)(f2 + j0 + 4);
      float fj[8] = {u0.x, u0.y, u0.z, u0.w, u1.x, u1.y, u1.z, u1.w};
      unsigned int mb = (unsigned int)(mreg >> (t * 8)) & 0xff;
#pragma unroll
      for (int u = 0; u < 8; u++) {
        float a = __builtin_fmaf(LOG2E, fj[u], F1L);
        float e = fmaxf(a, 0.2f * a);
        mx = fmaxf(mx, ((mb >> u) & 1) ? e : -INFINITY);
      }
    }
#pragma unroll
    for (int off = 1; off < TPR; off <<= 1) mx = fmaxf(mx, __shfl_xor(mx, off));
    float d = 0.f;
#pragma unroll
    for (int t = 0; t < NT; t++) {
      const int ch = pj + t * TPR;
      const int j0 = ch * 8;
      float4 u0 = *(const float4*)(f2 + j0);
      float4 u1 = *(const float4*)(f2 + j0 + 4);
      float fj[8] = {u0.x, u0.y, u0.z, u0.w, u1.x, u1.y, u1.z, u1.w};
      unsigned int mb = (unsigned int)(mreg >> (t * 8)) & 0xff;
      V16 pk;
#pragma unroll
      for (int u = 0; u < 8; u++) {
        float a = __builtin_fmaf(LOG2E, fj[u], F1L);
        float e = fmaxf(a, 0.2f * a);
        float p = ((mb >> u) & 1) ? exp2f(e - mx) : 0.f;
        pk.h[u] = (bf16)p;
        d += p;
      }
      *(uint4*)(sh.P + pchunk(pi, ch)) = pk.u;
    }
#pragma unroll
    for (int off = 1; off < TPR; off <<= 1) d += __shfl_xor(d, off);
    if (pj == 0) dinvs[pi] = (d > 0.f) ? (1.f / d) : 0.f;
  };

#pragma unroll 1
  for (int hh = 0; hh < NHB; hh++) {
    const int h = hp * NHB + hh;
    const int hb = h * 32 + bb;
    // coalesced frag base: chunk C = ((hb*16+ft)*16+js)*64 + lane
    const bf16* wfb = WhT + (long long)hb * 131072 + (long long)wave * 32768 + lane * 8;
    V16 bcur[4], bnxt[4];
#pragma unroll
    for (int ni = 0; ni < 4; ni++)       // js=0 prefetch: hides under buildP
      bcur[ni].u = *(const uint4*)(wfb + ni * 8192);
    barrier_lds();                        // prior head's P reads complete
    buildP(h);
    barrier_lds();                        // P + dinv visible to all waves
    f32x4 acc[MI][4];
#pragma unroll
    for (int i = 0; i < MI; i++)
#pragma unroll
      for (int j = 0; j < 4; j++) acc[i][j] = {0.f, 0.f, 0.f, 0.f};
#pragma unroll
    for (int js = 0; js < 16; js++) {
      if (js < 15) {
#pragma unroll
        for (int ni = 0; ni < 4; ni++)
          bnxt[ni].u = *(const uint4*)(wfb + ni * 8192 + (js + 1) * 512);
      }
      V16 af[MI];
#pragma unroll
      for (int mi = 0; mi < MI; mi++)
        af[mi].u = *(const uint4*)(sh.P + pchunk(mi * 16 + lrow, js * 4 + quad));
#pragma unroll
      for (int ni = 0; ni < 4; ni++)
#pragma unroll
        for (int mi = 0; mi < MI; mi++)
          acc[mi][ni] = __builtin_amdgcn_mfma_f32_16x16x32_bf16(af[mi].s, bcur[ni].s, acc[mi][ni], 0, 0, 0);
#pragma unroll
      for (int ni = 0; ni < 4; ni++) bcur[ni] = bnxt[ni];
    }
    float drow[MI][4];
#pragma unroll
    for (int mi = 0; mi < MI; mi++)
#pragma unroll
      for (int r = 0; r < 4; r++)
        drow[mi][r] = dinvs[mi * 16 + quad * 4 + r];
#pragma unroll
    for (int mi = 0; mi < MI; mi++)
#pragma unroll
      for (int ni = 0; ni < 4; ni++)
#pragma unroll
        for (int r = 0; r < 4; r++) {
          float v = acc[mi][ni][r] * drow[mi][r];
          hacc[mi][ni][r] += (MODE == 1) ? v
                           : (v > 0.f ? v : (exp2f(v * LOG2E) - 1.f));
        }
  }
  __syncthreads();                   // all MFMA P-reads done; hs aliases P
#pragma unroll
  for (int mi = 0; mi < MI; mi++)
#pragma unroll
    for (int ni = 0; ni < 4; ni++) {
      int f = wave * 64 + ni * 16 + lrow;
#pragma unroll
      for (int r = 0; r < 4; r++) {
        int row = mi * 16 + quad * 4 + r;
        sh.hs[row * 264 + f] = hacc[mi][ni][r];
      }
    }
  __syncthreads();
  const int fb = pj * CPT;
  float* op = (float*)(hp ? out1 : out0) +
              (((long long)bb * 512) + ibase + pi) * 256 + fb;
#pragma unroll
  for (int c0 = 0; c0 < CPT; c0 += 4) {
    float4 w;
    w.x = sh.hs[pi * 264 + fb + c0 + 0];
    w.y = sh.hs[pi * 264 + fb + c0 + 1];
    w.z = sh.hs[pi * 264 + fb + c0 + 2];
    w.w = sh.hs[pi * 264 + fb + c0 + 3];
    if (MODE == 1) {
      w.x = fmaxf(w.x, 0.f); w.y = fmaxf(w.y, 0.f);
      w.z = fmaxf(w.z, 0.f); w.w = fmaxf(w.w, 0.f);
    }
    *(float4*)(op + c0) = w;
  }
}

// ---- kernel 7: combine head-group partials: (a+b)*0.125 -> bf16 ---------
__global__ __launch_bounds__(256) void k_fin(const float* __restrict__ a,
                                             const float* __restrict__ b,
                                             bf16* __restrict__ dst) {
  long long i = ((long long)blockIdx.x * 256 + threadIdx.x) * 4;
  float4 x = *(const float4*)(a + i);
  float4 y = *(const float4*)(b + i);
  U8 w;
  w.h[0] = (bf16)((x.x + y.x) * 0.125f);
  w.h[1] = (bf16)((x.y + y.y) * 0.125f);
  w.h[2] = (bf16)((x.z + y.z) * 0.125f);
  w.h[3] = (bf16)((x.w + y.w) * 0.125f);
  *(ushort4*)(dst + i) = w.s;
}

extern "C" void kernel_launch(void* const* d_in, const int* in_sizes, int n_in,
                              void* d_out, int out_size, void* d_ws, size_t ws_size,
                              hipStream_t stream) {
  const float* x    = (const float*)d_in[0];
  const int*   adj  = (const int*)d_in[1];
  const float* W0   = (const float*)d_in[2];
  const float* a1_0 = (const float*)d_in[3];
  const float* a2_0 = (const float*)d_in[4];
  const float* Wo   = (const float*)d_in[5];
  const float* a1_o = (const float*)d_in[6];
  const float* a2_o = (const float*)d_in[7];

  char* p = (char*)d_ws;
  auto take = [&](size_t n) { char* r = p; p += (n + 255) & ~(size_t)255; return r; };
  unsigned long long* maskb = (unsigned long long*)take(32ull * 512 * 8 * 8);
  bf16*  xb   = (bf16*)take(32ull * 512 * 768 * 2);   // 24 MB; reused below
  bf16*  W0T  = (bf16*)take(8ull * 256 * 768 * 2);
  bf16*  WoT  = (bf16*)take(256ull * 256 * 2);
  bf16*  WhT  = (bf16*)take(8ull * 32 * 256 * 512 * 2);
  float* f1p1 = (float*)take(8ull * 32 * 512 * 4);   // contiguous zero-range start
  float* f2p1 = (float*)take(8ull * 32 * 512 * 4);
  float* f1p2 = (float*)take(32ull * 512 * 4);
  float* f2p2 = (float*)take(32ull * 512 * 4);       // contiguous zero-range end
  float* pv1  = (float*)take(32ull * 512 * 256 * 4); // head-group partial 1 (16 MB)
  // xb region (24 MB) is dead after layer-1 GEMM: reuse front 16 MB for
  // head-group partial 0, back 8 MB for h_mid bf16.
  float* pv0  = (float*)xb;
  bf16*  hmid = (bf16*)((char*)xb + 16ull * 1024 * 1024);
  bf16*  Wh2T = WhT;   // WhT dead after pv1; reuse for layer-2

  // zero f1p1..f2p2 (2*524288 + 2*65536 bytes = 73728 float4)
  k_zero<<<288, 256, 0, stream>>>((float4*)f1p1, 73728);
  k_cvt<<<6144, 256, 0, stream>>>(x, xb, 32ll * 512 * 768);
  k_maskpack<<<32768, 256, 0, stream>>>(adj, maskb);
  k_transpose<<<dim3(8, 24, 8), 256, 0, stream>>>(W0, W0T, 768, 256);
  k_transpose<<<dim3(8, 8, 1), 256, 0, stream>>>(Wo, WoT, 256, 256);
  // layer 1
  k_gemm<<<dim3(2, 128, 8), 256, 0, stream>>>(xb, W0T, WhT, 768,
                                              a1_0, a2_0, 256, f1p1, f2p1);
  k_pv<2, 4, 32, 0><<<1024, 256, 0, stream>>>(WhT, f1p1, f2p1, maskb, pv0, pv1);
  k_fin<<<4096, 256, 0, stream>>>(pv0, pv1, hmid);
  // layer 2
  k_gemm<<<dim3(2, 128, 1), 256, 0, stream>>>(hmid, WoT, Wh2T, 256,
                                              a1_o, a2_o, 0, f1p2, f2p2);
  k_pv<1, 1, 16, 1><<<1024, 256, 0, stream>>>(Wh2T, f1p2, f2p2, maskb, d_out, nullptr);
}

// Round 6
// 401.726 us; speedup vs baseline: 1.2728x; 1.2728x over previous
//
#include <hip/hip_runtime.h>
#include <hip/hip_bf16.h>
#include <stdint.h>

typedef __bf16 bf16;
typedef short short8 __attribute__((ext_vector_type(8)));   // bf16 A/B frag (bit pattern)
typedef float f32x4 __attribute__((ext_vector_type(4)));

#define LOG2E 1.4426950408889634f

union V16 { uint4 u; short8 s; bf16 h[8]; };
union U8  { ushort4 s; bf16 h[4]; };

typedef const __attribute__((address_space(1))) void* gp_t;
typedef __attribute__((address_space(3))) void* lp_t;
__device__ __forceinline__ void gld16(const bf16* g, bf16* l) {
  __builtin_amdgcn_global_load_lds((gp_t)g, (lp_t)l, 16, 0, 0);
}

// ---- kernel Z: zero a float4 range ---------------------------------------
__global__ __launch_bounds__(256) void k_zero(float4* __restrict__ p, int n4) {
  int i = blockIdx.x * 256 + threadIdx.x;
  if (i < n4) p[i] = {0.f, 0.f, 0.f, 0.f};
}

// ---- kernel 0: f32 -> bf16 bulk convert (n multiple of 8) ---------------
__global__ __launch_bounds__(256) void k_cvt(const float* __restrict__ src,
                                             bf16* __restrict__ dst, long long n) {
  long long i = ((long long)blockIdx.x * 256 + threadIdx.x) * 8;
  if (i >= n) return;
  float4 a = *(const float4*)(src + i);
  float4 b = *(const float4*)(src + i + 4);
  U8 w0, w1;
  w0.h[0] = (bf16)a.x; w0.h[1] = (bf16)a.y; w0.h[2] = (bf16)a.z; w0.h[3] = (bf16)a.w;
  w1.h[0] = (bf16)b.x; w1.h[1] = (bf16)b.y; w1.h[2] = (bf16)b.z; w1.h[3] = (bf16)b.w;
  *(ushort4*)(dst + i)     = w0.s;
  *(ushort4*)(dst + i + 4) = w1.s;
}

// ---- kernel 1: pack adjacency rows into 512-bit masks -------------------
__global__ __launch_bounds__(256) void k_maskpack(const int* __restrict__ adj,
                                                  unsigned long long* __restrict__ mask) {
  int wid = blockIdx.x * 4 + (threadIdx.x >> 6);
  int lane = threadIdx.x & 63;
  int a = adj[(long long)wid * 64 + lane];
  unsigned long long m = __ballot(a > 0);
  if (lane == 0) mask[wid] = m;
}

// ---- kernel 2: f32 [R,C] -> bf16 [C,R] transpose+convert per z-slice ----
__global__ __launch_bounds__(256) void k_transpose(const float* __restrict__ src,
                                                   bf16* __restrict__ dst, int R, int C) {
  __shared__ float t[32][33];
  int c0 = blockIdx.x * 32, r0 = blockIdx.y * 32;
  src += (long long)blockIdx.z * R * C;
  dst += (long long)blockIdx.z * R * C;
  int tx = threadIdx.x & 31, ty = threadIdx.x >> 5;
  for (int rr = ty; rr < 32; rr += 8)
    t[rr][tx] = src[(long long)(r0 + rr) * C + (c0 + tx)];
  __syncthreads();
  for (int cc = ty; cc < 32; cc += 8)
    dst[(long long)(c0 + cc) * R + (r0 + tx)] = (bf16)t[tx][cc];
}

// ---- kernel 3: bf16 MFMA GEMM + fused f1/f2 dot epilogue ----------------
// Output layout: MFMA-fragment-swizzled Wf. 8-bf16 chunk index:
//   C = ((hb*16 + ft)*16 + js)*64 + quad*16 + lrow
// A k_pv wave then reads frag (ni,js) as base + lane*8 elems: coalesced 1KB.
__global__ __launch_bounds__(256) void k_gemm(const bf16* __restrict__ A,
                                              const bf16* __restrict__ WT,
                                              bf16* __restrict__ outT, int K,
                                              const float* __restrict__ a1,
                                              const float* __restrict__ a2,
                                              int aStride,
                                              float* __restrict__ f1out,
                                              float* __restrict__ f2out) {
  __shared__ bf16 As[128 * 32];      // unpadded: global_load_lds lane order
  __shared__ bf16 Bs[128 * 32];
  const int nb = blockIdx.x, mb = blockIdx.y, h = blockIdx.z;
  const int tid = threadIdx.x, wave = tid >> 6, lane = tid & 63;
  const int lrow = lane & 15, quad = lane >> 4;
  const long long mbase = (long long)mb * 128;
  const int nbase = nb * 128;
  const bf16* W = WT + (long long)h * 256 * K;
  const int wm = (wave >> 1) * 64, wn = (wave & 1) * 64;
  const int srow = wave * 16 + (lane >> 2);
  const int skoff = (lane & 3) * 8;
  const bf16* ag0 = A + (mbase + srow) * K + skoff;
  const bf16* ag1 = ag0 + 64 * K;
  const bf16* bg0 = W + (long long)(nbase + srow) * K + skoff;
  const bf16* bg1 = bg0 + 64 * K;
  bf16* lA0 = As + wave * 16 * 32;
  bf16* lA1 = As + (64 + wave * 16) * 32;
  bf16* lB0 = Bs + wave * 16 * 32;
  bf16* lB1 = Bs + (64 + wave * 16) * 32;
  f32x4 acc[4][4];
#pragma unroll
  for (int i = 0; i < 4; i++)
#pragma unroll
    for (int j = 0; j < 4; j++) acc[i][j] = {0.f, 0.f, 0.f, 0.f};
  for (int k0 = 0; k0 < K; k0 += 32) {
    __syncthreads();                 // prior frag reads complete before overwrite
    gld16(ag0 + k0, lA0);
    gld16(ag1 + k0, lA1);
    gld16(bg0 + k0, lB0);
    gld16(bg1 + k0, lB1);
    __syncthreads();                 // vmcnt(0) drain: tile landed
    V16 af[4], bfx[4];
#pragma unroll
    for (int mi = 0; mi < 4; mi++)
      af[mi].u = *(const uint4*)(As + (wm + mi * 16 + lrow) * 32 + quad * 8);
#pragma unroll
    for (int ni = 0; ni < 4; ni++)
      bfx[ni].u = *(const uint4*)(Bs + (wn + ni * 16 + lrow) * 32 + quad * 8);
#pragma unroll
    for (int mi = 0; mi < 4; mi++)
#pragma unroll
      for (int ni = 0; ni < 4; ni++)
        acc[mi][ni] = __builtin_amdgcn_mfma_f32_16x16x32_bf16(af[mi].s, bfx[ni].s, acc[mi][ni], 0, 0, 0);
  }
  // D frag: col(lane&15) -> f, row(quad*4+r) -> node; write frag-swizzled
#pragma unroll
  for (int mi = 0; mi < 4; mi++) {
    long long m0 = mbase + wm + mi * 16 + quad * 4;
    int bbi = (int)(m0 >> 9);
    int jj = (int)(m0 & 511);
    int js = jj >> 5, qp = (jj >> 3) & 3, eo = jj & 7;
    long long rowbase = (long long)(h * 32 + bbi) * 131072 +
                        (long long)js * 512 + (qp * 16 + lrow) * 8 + eo;
#pragma unroll
    for (int ni = 0; ni < 4; ni++) {
      int ft = ((nbase + wn) >> 4) + ni;
      U8 w;
#pragma unroll
      for (int r = 0; r < 4; r++) w.h[r] = (bf16)acc[mi][ni][r];
      *(ushort4*)(outT + rowbase + (long long)ft * 8192) = w.s;
    }
  }
  // ---- fused f1/f2 partial dots (raw units; LOG2E applied downstream) ----
  float av1[4], av2[4];
#pragma unroll
  for (int ni = 0; ni < 4; ni++) {
    int f = nbase + wn + ni * 16 + lrow;
    av1[ni] = a1[h * aStride + f];
    av2[ni] = a2[h * aStride + f];
  }
#pragma unroll
  for (int mi = 0; mi < 4; mi++) {
#pragma unroll
    for (int r = 0; r < 4; r++) {
      float s1 = 0.f, s2 = 0.f;
#pragma unroll
      for (int ni = 0; ni < 4; ni++) {
        s1 = __builtin_fmaf(acc[mi][ni][r], av1[ni], s1);
        s2 = __builtin_fmaf(acc[mi][ni][r], av2[ni], s2);
      }
#pragma unroll
      for (int off = 1; off < 16; off <<= 1) {
        s1 += __shfl_xor(s1, off);
        s2 += __shfl_xor(s2, off);
      }
      if (lrow == 0) {
        long long m0 = mbase + wm + mi * 16 + quad * 4 + r;
        atomicAdd(&f1out[(long long)h * 16384 + m0], s1);
        atomicAdd(&f2out[(long long)h * 16384 + m0], s2);
      }
    }
  }
}

// ---- kernel 5: softmax constants c_i = M_i + log2(d_i), inputs raw ------
__global__ __launch_bounds__(256) void k_passA(const float* __restrict__ f1p,
                                               const float* __restrict__ f2p,
                                               const unsigned long long* __restrict__ mask,
                                               float* __restrict__ cc) {
  const int hb = blockIdx.x, bb = hb & 31;
  const int wave = threadIdx.x >> 6, lane = threadIdx.x & 63;
  const int i = blockIdx.y * 4 + wave;
  const float* f2 = f2p + hb * 512;
  float4 va = *(const float4*)(f2 + lane * 8);
  float4 vb = *(const float4*)(f2 + lane * 8 + 4);
  float vj[8] = {va.x, va.y, va.z, va.w, vb.x, vb.y, vb.z, vb.w};
  unsigned int mb = ((const unsigned char*)(mask + ((long long)bb * 512 + i) * 8))[lane];
  float f1 = f1p[hb * 512 + i];
  float m = -INFINITY;
#pragma unroll
  for (int t = 0; t < 8; t++)
    if ((mb >> t) & 1) m = fmaxf(m, vj[t]);
#pragma unroll
  for (int off = 32; off; off >>= 1) m = fmaxf(m, __shfl_xor(m, off));
  float s = f1 + m;
  float M2 = LOG2E * fmaxf(s, 0.2f * s);       // scaled max score (log2 units)
  float d = 0.f;
#pragma unroll
  for (int t = 0; t < 8; t++) {
    float e0 = f1 + vj[t];
    float e = fmaxf(e0, 0.2f * e0);
    float p = exp2f(__builtin_fmaf(LOG2E, e, -M2));
    d += ((mb >> t) & 1) ? p : 0.f;
  }
#pragma unroll
  for (int off = 32; off; off >>= 1) d += __shfl_xor(d, off);
  if (lane == 0) {
    float cv = M2 + log2f(d);
    if (!isfinite(M2) || !(d > 0.f)) cv = INFINITY;  // fully-masked row -> P=0
    cc[hb * 512 + i] = cv;
  }
}

// ---- kernel 6: fused masked-softmax PV, grid-parallel over head-groups --
// Grid = NSPLIT * 32 * (512/ROWS) blocks; id low bits = bb (XCD/L2 locality).
// Each block: builds P (ROWS x 512) in LDS per head; js-loop reads B
// fragments from the frag-swizzled Wf layout: ONE coalesced 1KB wave-read
// per (ni,js) -- 16 cache lines/instr, every byte used.
// ROWS=16 (layer 1): 18 KB LDS -> ~8 blocks/CU by LDS, ~5 by VGPR; doubles
// resident waves vs ROWS=32 to hide B-load latency (R3->R6 single change).
// MODE0: elu + head-partial sum -> f32 partial buffer out0/out1 (by hp).
// MODE1: relu -> f32 final output.
__device__ __forceinline__ int pchunk(int row, int c) {   // bf16 index of 8-elem chunk
  return row * 512 + (((c + 3 * row) & 63) << 3);
}

template <int NSPLIT, int NHB, int ROWS, int MODE>
__global__ __launch_bounds__(256) void k_pv(const bf16* __restrict__ WhT,
                                            const float* __restrict__ f1p,
                                            const float* __restrict__ cc,
                                            const float* __restrict__ f2p,
                                            const unsigned long long* __restrict__ mask,
                                            void* __restrict__ out0,
                                            void* __restrict__ out1) {
  constexpr int TPR = 256 / ROWS;          // threads per P row (8 or 16)
  constexpr int NT  = 64 / TPR;            // mask bytes (col-chunks) per thread
  constexpr int MI  = ROWS / 16;           // 16-row MFMA sub-blocks
  constexpr int RB  = 32 * (512 / ROWS);   // blocks per head-group
  constexpr int CPT = 256 / TPR;           // output cols per thread
  __shared__ union { bf16 P[ROWS * 512]; float hs[ROWS * 264]; } sh;
  __shared__ unsigned char ms[ROWS * 64];
  const int id = blockIdx.x;
  const int hp = id / RB;                  // head-group index (0..NSPLIT-1)
  const int rid = id % RB;
  const int bb = rid & 31, it = rid >> 5;
  const int ibase = it * ROWS;
  const int tid = threadIdx.x, wave = tid >> 6, lane = tid & 63;
  const int lrow = lane & 15, quad = lane >> 4;
  const int pi = tid / TPR;                // P row
  const int pj = tid % TPR;                // column-chunk owner within the row
  {
    const uint4* msrc = (const uint4*)(mask + ((long long)bb * 512 + ibase) * 8);
    if (tid < ROWS * 4) ((uint4*)ms)[tid] = msrc[tid];
  }
  __syncthreads();
  unsigned long long mreg = 0;
#pragma unroll
  for (int t = 0; t < NT; t++)
    mreg |= (unsigned long long)ms[pi * 64 + pj + t * TPR] << (t * 8);
  f32x4 hacc[MI][4];
#pragma unroll
  for (int i = 0; i < MI; i++)
#pragma unroll
    for (int j = 0; j < 4; j++) hacc[i][j] = {0.f, 0.f, 0.f, 0.f};

  auto buildP = [&](int h) {
    const int hb = h * 32 + bb;
    const float f1v = f1p[hb * 512 + ibase + pi];
    const float cv  = cc[hb * 512 + ibase + pi];
    const float Ac = __builtin_fmaf(LOG2E, f1v, -cv);
    const float Bc = __builtin_fmaf(0.2f * LOG2E, f1v, -cv);
    const float* f2 = f2p + hb * 512;
#pragma unroll
    for (int t = 0; t < NT; t++) {
      const int ch = pj + t * TPR;         // col-chunk index 0..63
      const int j0 = ch * 8;
      float4 u0 = *(const float4*)(f2 + j0);
      float4 u1 = *(const float4*)(f2 + j0 + 4);
      float fj[8] = {u0.x, u0.y, u0.z, u0.w, u1.x, u1.y, u1.z, u1.w};
      unsigned int mb = (unsigned int)(mreg >> (t * 8)) & 0xff;
      V16 pk;
#pragma unroll
      for (int u = 0; u < 8; u++) {
        float e = fmaxf(__builtin_fmaf(LOG2E, fj[u], Ac),
                        __builtin_fmaf(0.2f * LOG2E, fj[u], Bc));
        float p = ((mb >> u) & 1) ? exp2f(e) : 0.f;
        pk.h[u] = (bf16)p;
      }
      *(uint4*)(sh.P + pchunk(pi, ch)) = pk.u;
    }
  };

#pragma unroll 1
  for (int hh = 0; hh < NHB; hh++) {
    const int h = hp * NHB + hh;
    const int hb = h * 32 + bb;
    __syncthreads();                  // prior head's P reads complete
    buildP(h);
    __syncthreads();                  // P ready for all waves
    // coalesced frag base: chunk C = ((hb*16+ft)*16+js)*64 + lane
    const bf16* wfb = WhT + (long long)hb * 131072 + (long long)wave * 32768 + lane * 8;
    f32x4 acc[MI][4];
#pragma unroll
    for (int i = 0; i < MI; i++)
#pragma unroll
      for (int j = 0; j < 4; j++) acc[i][j] = {0.f, 0.f, 0.f, 0.f};
#pragma unroll
    for (int js = 0; js < 16; js++) {
      V16 af[MI], bfr[4];
#pragma unroll
      for (int mi = 0; mi < MI; mi++)
        af[mi].u = *(const uint4*)(sh.P + pchunk(mi * 16 + lrow, js * 4 + quad));
#pragma unroll
      for (int ni = 0; ni < 4; ni++)
        bfr[ni].u = *(const uint4*)(wfb + ni * 8192 + js * 512);
#pragma unroll
      for (int ni = 0; ni < 4; ni++)
#pragma unroll
        for (int mi = 0; mi < MI; mi++)
          acc[mi][ni] = __builtin_amdgcn_mfma_f32_16x16x32_bf16(af[mi].s, bfr[ni].s, acc[mi][ni], 0, 0, 0);
    }
#pragma unroll
    for (int mi = 0; mi < MI; mi++)
#pragma unroll
      for (int ni = 0; ni < 4; ni++)
#pragma unroll
        for (int r = 0; r < 4; r++) {
          float v = acc[mi][ni][r];
          hacc[mi][ni][r] += (MODE == 1) ? v
                           : (v > 0.f ? v : (exp2f(v * LOG2E) - 1.f));
        }
  }
  __syncthreads();                   // all MFMA P-reads done; hs aliases P
#pragma unroll
  for (int mi = 0; mi < MI; mi++)
#pragma unroll
    for (int ni = 0; ni < 4; ni++) {
      int f = wave * 64 + ni * 16 + lrow;
#pragma unroll
      for (int r = 0; r < 4; r++) {
        int row = mi * 16 + quad * 4 + r;
        sh.hs[row * 264 + f] = hacc[mi][ni][r];
      }
    }
  __syncthreads();
  const int fb = pj * CPT;
  float* op = (float*)(hp ? out1 : out0) +
              (((long long)bb * 512) + ibase + pi) * 256 + fb;
#pragma unroll
  for (int c0 = 0; c0 < CPT; c0 += 4) {
    float4 w;
    w.x = sh.hs[pi * 264 + fb + c0 + 0];
    w.y = sh.hs[pi * 264 + fb + c0 + 1];
    w.z = sh.hs[pi * 264 + fb + c0 + 2];
    w.w = sh.hs[pi * 264 + fb + c0 + 3];
    if (MODE == 1) {
      w.x = fmaxf(w.x, 0.f); w.y = fmaxf(w.y, 0.f);
      w.z = fmaxf(w.z, 0.f); w.w = fmaxf(w.w, 0.f);
    }
    *(float4*)(op + c0) = w;
  }
}

// ---- kernel 7: combine head-group partials: (a+b)*0.125 -> bf16 ---------
__global__ __launch_bounds__(256) void k_fin(const float* __restrict__ a,
                                             const float* __restrict__ b,
                                             bf16* __restrict__ dst) {
  long long i = ((long long)blockIdx.x * 256 + threadIdx.x) * 4;
  float4 x = *(const float4*)(a + i);
  float4 y = *(const float4*)(b + i);
  U8 w;
  w.h[0] = (bf16)((x.x + y.x) * 0.125f);
  w.h[1] = (bf16)((x.y + y.y) * 0.125f);
  w.h[2] = (bf16)((x.z + y.z) * 0.125f);
  w.h[3] = (bf16)((x.w + y.w) * 0.125f);
  *(ushort4*)(dst + i) = w.s;
}

extern "C" void kernel_launch(void* const* d_in, const int* in_sizes, int n_in,
                              void* d_out, int out_size, void* d_ws, size_t ws_size,
                              hipStream_t stream) {
  const float* x    = (const float*)d_in[0];
  const int*   adj  = (const int*)d_in[1];
  const float* W0   = (const float*)d_in[2];
  const float* a1_0 = (const float*)d_in[3];
  const float* a2_0 = (const float*)d_in[4];
  const float* Wo   = (const float*)d_in[5];
  const float* a1_o = (const float*)d_in[6];
  const float* a2_o = (const float*)d_in[7];

  char* p = (char*)d_ws;
  auto take = [&](size_t n) { char* r = p; p += (n + 255) & ~(size_t)255; return r; };
  unsigned long long* maskb = (unsigned long long*)take(32ull * 512 * 8 * 8);
  bf16*  xb   = (bf16*)take(32ull * 512 * 768 * 2);   // 24 MB; reused below
  bf16*  W0T  = (bf16*)take(8ull * 256 * 768 * 2);
  bf16*  WoT  = (bf16*)take(256ull * 256 * 2);
  bf16*  WhT  = (bf16*)take(8ull * 32 * 256 * 512 * 2);
  float* f1p1 = (float*)take(8ull * 32 * 512 * 4);   // contiguous zero-range start
  float* f2p1 = (float*)take(8ull * 32 * 512 * 4);
  float* f1p2 = (float*)take(32ull * 512 * 4);
  float* f2p2 = (float*)take(32ull * 512 * 4);       // contiguous zero-range end
  float* c1   = (float*)take(8ull * 32 * 512 * 4);
  float* c2   = (float*)take(32ull * 512 * 4);
  float* pv1  = (float*)take(32ull * 512 * 256 * 4); // head-group partial 1 (16 MB)
  // xb region (24 MB) is dead after layer-1 GEMM: reuse front 16 MB for
  // head-group partial 0, back 8 MB for h_mid bf16.
  float* pv0  = (float*)xb;
  bf16*  hmid = (bf16*)((char*)xb + 16ull * 1024 * 1024);
  bf16*  Wh2T = WhT;   // WhT dead after pv1; reuse for layer-2

  // zero f1p1..f2p2 (2*524288 + 2*65536 bytes = 73728 float4)
  k_zero<<<288, 256, 0, stream>>>((float4*)f1p1, 73728);
  k_cvt<<<6144, 256, 0, stream>>>(x, xb, 32ll * 512 * 768);
  k_maskpack<<<32768, 256, 0, stream>>>(adj, maskb);
  k_transpose<<<dim3(8, 24, 8), 256, 0, stream>>>(W0, W0T, 768, 256);
  k_transpose<<<dim3(8, 8, 1), 256, 0, stream>>>(Wo, WoT, 256, 256);
  // layer 1
  k_gemm<<<dim3(2, 128, 8), 256, 0, stream>>>(xb, W0T, WhT, 768,
                                              a1_0, a2_0, 256, f1p1, f2p1);
  k_passA<<<dim3(256, 128), 256, 0, stream>>>(f1p1, f2p1, maskb, c1);
  k_pv<2, 4, 16, 0><<<2048, 256, 0, stream>>>(WhT, f1p1, c1, f2p1, maskb, pv0, pv1);
  k_fin<<<4096, 256, 0, stream>>>(pv0, pv1, hmid);
  // layer 2
  k_gemm<<<dim3(2, 128, 1), 256, 0, stream>>>(hmid, WoT, Wh2T, 256,
                                              a1_o, a2_o, 0, f1p2, f2p2);
  k_passA<<<dim3(32, 128), 256, 0, stream>>>(f1p2, f2p2, maskb, c2);
  k_pv<1, 1, 16, 1><<<1024, 256, 0, stream>>>(Wh2T, f1p2, c2, f2p2, maskb, d_out, nullptr);
}